// Round 8
// baseline (165.279 us; speedup 1.0000x reference)
//
#include <hip/hip_runtime.h>

typedef _Float16 half2 __attribute__((ext_vector_type(2)));
typedef _Float16 half4 __attribute__((ext_vector_type(4)));
typedef _Float16 half8 __attribute__((ext_vector_type(8)));
typedef float    f32x4 __attribute__((ext_vector_type(4)));

#define MFMA16(a,b,c) __builtin_amdgcn_mfma_f32_16x16x16f16((a),(b),(c),0,0,0)

static constexpr int N_NODES = 200000;
static constexpr int N_WIN   = N_NODES / 32;      // 6250 exact 32-node windows

// ---- workspace byte offsets ----
static constexpr size_t WS_ZWT = 0;        // [64][128][16] f16 : (z@W1)^T per graph, d-major k-inner
static constexpr size_t WS_W2T = 262144;   // [128][128] f16    : W2T[d_out][d_in]
static constexpr size_t WS_WHT = 294912;   // [16][128]  f16    : rows 0..3 = [Wp|Wv]^T, rest zero

// ---------------- prep: W2T + WhT + zW1^T ----------------
__global__ __launch_bounds__(256) void gnn_prep(
    const float* __restrict__ z,
    const float* __restrict__ W1,
    const float* __restrict__ W2,
    const float* __restrict__ Wp,
    const float* __restrict__ Wv,
    _Float16* __restrict__ zwt,
    _Float16* __restrict__ w2t,
    _Float16* __restrict__ wht)
{
    const int b = blockIdx.x, t = threadIdx.x;
    if (b < 64) {
        const int e = b * 256 + t;            // 0..16383
        const int n = e >> 7, kk = e & 127;   // w2t[n][kk] = W2[kk][n]
        w2t[e] = (_Float16)W2[kk * 128 + n];
    } else if (b < 72) {
        const int e = (b - 64) * 256 + t;     // 0..2047
        const int j = e >> 7, d = e & 127;
        float v = 0.f;
        if (j < 2)      v = Wp[d * 2 + j];
        else if (j < 4) v = Wv[d * 2 + (j - 2)];
        wht[e] = (_Float16)v;
    } else {
        const int p = (b - 72) * 2 + (t >> 7);   // 0..1023 = (g,k) pairs
        const int g = p >> 4, k = p & 15, d = t & 127;
        const float* zr = z + (g * 16 + k) * 128;
        float a0 = 0.f, a1 = 0.f, a2 = 0.f, a3 = 0.f;
#pragma unroll 8
        for (int c = 0; c < 128; c += 4) {
            a0 += zr[c    ] * W1[(c    ) * 128 + d];   // W1 coalesced over d
            a1 += zr[c + 1] * W1[(c + 1) * 128 + d];
            a2 += zr[c + 2] * W1[(c + 2) * 128 + d];
            a3 += zr[c + 3] * W1[(c + 3) * 128 + d];
        }
        zwt[(g * 128 + d) * 16 + k] = (_Float16)((a0 + a1) + (a2 + a3));
    }
}

__device__ inline float fast_tanh(float x) {
    x = fminf(fmaxf(x, -15.f), 15.f);
    const float e = __expf(2.f * x);
    return (e - 1.f) / (e + 1.f);
}

__device__ inline half4 cvt4(const f32x4 v) {
    half4 r;
    *(half2*)&r       = __builtin_bit_cast(half2, __builtin_amdgcn_cvt_pkrtz(v[0], v[1]));
    *((half2*)&r + 1) = __builtin_bit_cast(half2, __builtin_amdgcn_cvt_pkrtz(v[2], v[3]));
    return r;
}

__device__ inline half4 relu_cvt4(const f32x4 v) {
    half4 r;
    *(half2*)&r       = __builtin_bit_cast(half2, __builtin_amdgcn_cvt_pkrtz(fmaxf(v[0], 0.f), fmaxf(v[1], 0.f)));
    *((half2*)&r + 1) = __builtin_bit_cast(half2, __builtin_amdgcn_cvt_pkrtz(fmaxf(v[2], 0.f), fmaxf(v[3], 0.f)));
    return r;
}

// ---------------- main: K-chunk-outer structure ----------------
// acc2[2][8] (64 regs) is touched ONLY by MFMA C/D inside the mt loop -> AGPR-placed.
// Everything VALU-touched (h1 chunk, GEMM1 accs) is transient per-mt. No 64-reg
// arch-VGPR object survives a window -> no spill at the 84-reg (256,3) arch half.
__global__ __launch_bounds__(256, 3) void gnn_main(
    const float* __restrict__ s,
    const int* __restrict__ batch,
    const float* __restrict__ b1,
    const float* __restrict__ b2,
    const float* __restrict__ bp,
    const float* __restrict__ bv,
    const _Float16* __restrict__ zwt,
    const _Float16* __restrict__ w2t,
    const _Float16* __restrict__ wht,
    float* __restrict__ out)
{
    __shared__ char lds[37888];
    half8* a2l = (half8*)lds;                 // [mt*4+mop][lane] : GEMM2 A-frags, mo=2*mop(lo),2*mop+1(hi)
    half4* a3l = (half4*)(lds + 32768);       // [mo][lane]       : head A-frags
    float* b1l = (float*)(lds + 36864);
    float* b2l = (float*)(lds + 37376);

    const int tid  = threadIdx.x;
    const int lane = tid & 63;
    const int n16  = lane & 15;
    const int quad = lane >> 4;

    // ---- stage weights into LDS ----
#pragma unroll
    for (int r = 0; r < 8; ++r) {
        const int e   = r * 256 + tid;        // 0..2047
        const int mt  = e >> 8, mop = (e >> 6) & 3, ll = e & 63;
        const int nn  = ll & 15, qq = ll >> 4;
        const _Float16* s0 = w2t + ((2 * mop    ) * 16 + nn) * 128 + mt * 16 + qq * 4;
        const _Float16* s1 = w2t + ((2 * mop + 1) * 16 + nn) * 128 + mt * 16 + qq * 4;
        half8 v;
        *(half4*)&v       = *(const half4*)s0;
        *((half4*)&v + 1) = *(const half4*)s1;
        a2l[e] = v;
    }
#pragma unroll
    for (int r = 0; r < 2; ++r) {
        const int ee = r * 256 + tid;         // 0..511 : [mo][lane]
        const int tt = ee >> 6, ll = ee & 63;
        const int nn = ll & 15, qq = ll >> 4;
        a3l[ee] = *(const half4*)(wht + nn * 128 + tt * 16 + qq * 4);
    }
    if (tid < 128)      b1l[tid] = b1[tid];
    else                b2l[tid - 128] = b2[tid - 128];
    __syncthreads();

    f32x4 c3init = {0.f, 0.f, 0.f, 0.f};
    if (quad == 0) { c3init[0] = bp[0]; c3init[1] = bp[1]; c3init[2] = bv[0]; c3init[3] = bv[1]; }

    const int wid = blockIdx.x * 4 + (tid >> 6);
    const int nw  = gridDim.x * 4;            // 3072 waves

    const half4 z4 = {(_Float16)0.f, (_Float16)0.f, (_Float16)0.f, (_Float16)0.f};

    for (int w = wid; w < N_WIN; w += nw) {
        const int base = w * 32;

        const int gLo = batch[base];
        const int gHi = batch[base + 31];
        const int bg0 = batch[base + n16];
        const int bg1 = batch[base + 16 + n16];

        const f32x4 sv0 = *(const f32x4*)(s + (base + n16) * 16 + quad * 4);
        const f32x4 sv1 = *(const f32x4*)(s + (base + 16 + n16) * 16 + quad * 4);
        const half4 bs0 = cvt4(sv0);
        const half4 bs1 = cvt4(sv1);
        const half4 bm0 = (bg0 == gLo) ? bs0 : z4;   // mask vs base graph (== bs for 99% windows)
        const half4 bm1 = (bg1 == gLo) ? bs1 : z4;

        // prefetch all GEMM1 A-frags for base graph (16 VGPR, read-only)
        const _Float16* zg = zwt + gLo * 2048;
        half4 a1p[8];
#pragma unroll
        for (int mt = 0; mt < 8; ++mt)
            a1p[mt] = *(const half4*)(zg + (mt * 16 + n16) * 16 + quad * 4);

        // GEMM2 accumulator tile: MFMA-only until epilogue -> AGPR
        f32x4 acc2[2][8];
#pragma unroll
        for (int mo = 0; mo < 8; ++mo) {
            const f32x4 cb2 = *(const f32x4*)(b2l + mo * 16 + quad * 4);
            acc2[0][mo] = cb2;
            acc2[1][mo] = cb2;
        }

#pragma unroll
        for (int mt = 0; mt < 8; ++mt) {
            // GEMM1 K-chunk: bias-init C, transient accumulators
            const f32x4 cb1 = *(const f32x4*)(b1l + mt * 16 + quad * 4);
            f32x4 g1a = MFMA16(a1p[mt], bm0, cb1);
            f32x4 g1b = MFMA16(a1p[mt], bm1, cb1);
            if (gLo != gHi) {                 // rare wave-uniform boundary path
                for (int g = gLo + 1; g <= gHi; ++g) {
                    const half4 a1 = *(const half4*)(zwt + (g * 128 + mt * 16 + n16) * 16 + quad * 4);
                    g1a = MFMA16(a1, (bg0 == g) ? bs0 : z4, g1a);
                    g1b = MFMA16(a1, (bg1 == g) ? bs1 : z4, g1b);
                }
            }
            const half4 h1a = relu_cvt4(g1a);  // transient B-frag for GEMM2
            const half4 h1b = relu_cvt4(g1b);

            // 16 independent rank-16 updates into the AGPR tile
#pragma unroll
            for (int mop = 0; mop < 4; ++mop) {
                const half8 ww = a2l[(mt * 4 + mop) * 64 + lane];
                const half4 wlo = {ww[0], ww[1], ww[2], ww[3]};
                const half4 whi = {ww[4], ww[5], ww[6], ww[7]};
                acc2[0][2 * mop    ] = MFMA16(wlo, h1a, acc2[0][2 * mop    ]);
                acc2[0][2 * mop + 1] = MFMA16(whi, h1a, acc2[0][2 * mop + 1]);
                acc2[1][2 * mop    ] = MFMA16(wlo, h1b, acc2[1][2 * mop    ]);
                acc2[1][2 * mop + 1] = MFMA16(whi, h1b, acc2[1][2 * mop + 1]);
            }
        }

        // epilogue: relu + head MFMAs (transient h2), then store
        f32x4 acc3a = c3init, acc3b = c3init;
#pragma unroll
        for (int mo = 0; mo < 8; ++mo) {
            const half4 w3 = a3l[mo * 64 + lane];
            const half4 h2a = relu_cvt4(acc2[0][mo]);
            const half4 h2b = relu_cvt4(acc2[1][mo]);
            acc3a = MFMA16(w3, h2a, acc3a);
            acc3b = MFMA16(w3, h2b, acc3b);
        }

        if (quad == 0) {
            {
                const int node = base + n16;
                f32x4 o;
                o[0] = fast_tanh(acc3a[0]);
                o[1] = fast_tanh(acc3a[1]);
                o[2] = acc3a[2];
                o[3] = acc3a[3];
                *(f32x4*)(out + node * 4) = o;
            }
            {
                const int node = base + 16 + n16;
                f32x4 o;
                o[0] = fast_tanh(acc3b[0]);
                o[1] = fast_tanh(acc3b[1]);
                o[2] = acc3b[2];
                o[3] = acc3b[3];
                *(f32x4*)(out + node * 4) = o;
            }
        }
    }
}

extern "C" void kernel_launch(void* const* d_in, const int* in_sizes, int n_in,
                              void* d_out, int out_size, void* d_ws, size_t ws_size,
                              hipStream_t stream)
{
    const float* z     = (const float*)d_in[0];
    const float* s     = (const float*)d_in[1];
    const int*   batch = (const int*)d_in[2];
    const float* W1    = (const float*)d_in[3];
    const float* b1    = (const float*)d_in[4];
    const float* W2    = (const float*)d_in[5];
    const float* b2    = (const float*)d_in[6];
    const float* Wp    = (const float*)d_in[7];
    const float* bp    = (const float*)d_in[8];
    const float* Wv    = (const float*)d_in[9];
    const float* bv    = (const float*)d_in[10];
    float* out = (float*)d_out;

    char* w = (char*)d_ws;
    _Float16* zwt = (_Float16*)(w + WS_ZWT);
    _Float16* w2t = (_Float16*)(w + WS_W2T);
    _Float16* wht = (_Float16*)(w + WS_WHT);

    hipLaunchKernelGGL(gnn_prep, dim3(584), dim3(256), 0, stream,
                       z, W1, W2, Wp, Wv, zwt, w2t, wht);
    hipLaunchKernelGGL(gnn_main, dim3(768), dim3(256), 0, stream,
                       s, batch, b1, b2, bp, bv, zwt, w2t, wht, out);
}